// Round 6
// baseline (148.933 us; speedup 1.0000x reference)
//
#include <hip/hip_runtime.h>

// Problem constants (fixed by setup_inputs): x(64,32768,6) f32, templates(16,6,80), delays(16,6)
#define BB 64
#define SS 32768
#define FF 6
#define EE 16
#define LL 80
#define KK 480      // F*L
#define NSL 15      // K / 32
#define TBLK 256    // time positions per tile
#define NT 4        // tiles per block (1024 positions per block)
#define NPHI 4      // phases (t = t0 + phi + 4*row), one wave per phase
#define WROW 332    // xs row length in elems (exactly 332 needed)

typedef _Float16 half8 __attribute__((ext_vector_type(8)));
typedef float f32x4 __attribute__((ext_vector_type(4)));
typedef __fp16 h2 __attribute__((ext_vector_type(2)));

// Build reversed, delay-shifted kernel: wrev[e*480 + f*80 + r] = delayed[e,f,79-r]
__global__ void prep_kernel(const float* __restrict__ tpl, const float* __restrict__ dly,
                            _Float16* __restrict__ wrev) {
    int n = blockIdx.x * 256 + threadIdx.x;
    if (n >= EE * KK) return;
    int e = n / KK, k = n - e * KK;
    int f = k / LL, r = k - f * LL;
    int m = LL - 1 - r;
    float dl = fminf(fmaxf(dly[e * FF + f], -10.f), 10.f);
    int d = (int)rintf(dl);                 // RNE, matches jnp.round
    int src = m - d;
    float v = (src >= 0 && src < LL) ? tpl[(e * FF + f) * LL + src] : 0.f;
    wrev[n] = (_Float16)v;                  // NOT pre-scaled (avoid f16 denormals)
}

template <bool FROM_WS>
__global__ __launch_bounds__(256, 4) void corr_kernel(   // 4 waves/EU -> 128-VGPR budget
    const float* __restrict__ x, const float* __restrict__ tpl,
    const float* __restrict__ dly, const _Float16* __restrict__ wrev,
    float* __restrict__ out) {
    // One wave-private slab per wave; NO cross-wave sharing, NO barriers anywhere.
    __shared__ alignas(16) _Float16 xs[NPHI][FF][WROW];      // 15,936 B

    int tid = threadIdx.x;
    int lane = tid & 63;
    int w = tid >> 6;                     // wave id == phase
    int e = lane & 15;
    int g = lane >> 4;

    int b = blockIdx.x >> 5;              // 64 batches x 32 blocks
    int T0 = (blockIdx.x & 31) << 10;     // 1024 positions per block

    const float* xb = x + (size_t)b * (SS * FF);

    // ---- B fragments into registers (15 x 16B = 60 regs), pinned (compiler parks in AGPRs) ----
    f32x4 bqv[NSL];
    if constexpr (FROM_WS) {
        #pragma unroll
        for (int s = 0; s < NSL; s++)
            bqv[s] = *(const f32x4*)&wrev[e * KK + 32 * s + 8 * g];   // 16B aligned, L2/L3-hit
    } else {
        // fallback: compute own fragments directly (rarely used)
        #pragma unroll
        for (int s = 0; s < NSL; s++) {
            union { f32x4 f4; _Float16 h[8]; } u;
            #pragma unroll
            for (int j = 0; j < 8; j++) {
                int k = 32 * s + 8 * g + j;
                int f = k / LL, r = k - f * LL;
                int m = LL - 1 - r;
                float dl = fminf(fmaxf(dly[e * FF + f], -10.f), 10.f);
                int d = (int)rintf(dl);
                int src = m - d;
                u.h[j] = (_Float16)((src >= 0 && src < LL) ? tpl[(e * FF + f) * LL + src] : 0.f);
            }
            bqv[s] = u.f4;
        }
    }
    #pragma unroll
    for (int s = 0; s < NSL; s++)
        asm volatile("" : "+v"(bqv[s]));   // pin: cannot be sunk/rematerialized

    _Float16* xsw = &xs[w][0][0];          // wave-private [FF][WROW] slab

    for (int i = 0; i < NT; i++) {
        int t0 = T0 + (i << 8);
        int pbase = t0 + w - 39;           // wave-uniform window base

        // ---- stage own slab: 3 chunks of 64 position-pairs; ALL loads issued up-front ----
        float va[3][12];
        bool edge = (pbase < 0) | (pbase + 331 >= SS);   // wave-uniform
        if (!edge) {
            #pragma unroll
            for (int c = 0; c < 3; c++) {
                int pi = lane + 64 * c; if (pi > 165) pi = 165;   // dup-load, write-guarded below
                const float* xp = xb + (size_t)(pbase + 2 * pi) * FF;  // 12 contiguous floats, 8B-aligned
                #pragma unroll
                for (int q = 0; q < 6; q++)
                    *(float2*)&va[c][2 * q] = *(const float2*)&xp[2 * q];
            }
        } else {
            #pragma unroll
            for (int c = 0; c < 3; c++) {
                int pi = lane + 64 * c; if (pi > 165) pi = 165;
                int pos = pbase + 2 * pi;
                #pragma unroll
                for (int q = 0; q < 2; q++) {
                    int p = pos + q;
                    bool ok = (p >= 0) && (p < SS);
                    #pragma unroll
                    for (int f = 0; f < FF; f++)
                        va[c][q * 6 + f] = ok ? xb[(size_t)p * FF + f] : 0.f;
                }
            }
        }
        #pragma unroll
        for (int c = 0; c < 3; c++) {
            int pi = lane + 64 * c;
            if (pi < 166) {
                #pragma unroll
                for (int f = 0; f < FF; f++) {
                    h2 hp = __builtin_amdgcn_cvt_pkrtz(va[c][f], va[c][6 + f]);
                    *(h2*)&xsw[f * WROW + 2 * pi] = hp;     // 4B-aligned, bank-perfect
                }
            }
        }
        // (within-wave ds_write -> ds_read ordering: compiler inserts lgkmcnt)

        // ---- compute: 4 row-tiles x 15 K-slices; A via conflict-free b64 pairs ----
        f32x4 acc[4];
        #pragma unroll
        for (int tt = 0; tt < 4; tt++) acc[tt] = (f32x4){0.f, 0.f, 0.f, 0.f};
        const char* xph = (const char*)xsw;
        #pragma unroll
        for (int tt = 0; tt < 4; tt++) {
            int R = tt * 16 + e;          // A-row position index (t-stride 4)
            #pragma unroll
            for (int s = 0; s < NSL; s++) {
                int k0 = 32 * s + 8 * g;
                int f = (k0 * 205) >> 14;        // exact k0/80 for k0 in [0,480)
                int r0 = k0 - 80 * f;
                const char* p = xph + 2 * (f * WROW + 4 * R + r0);   // 8B-aligned
                uint2 lo = *(const uint2*)p;
                uint2 hi = *(const uint2*)(p + 8);
                union { unsigned u[4]; half8 h; } av;
                av.u[0] = lo.x; av.u[1] = lo.y; av.u[2] = hi.x; av.u[3] = hi.y;
                union { f32x4 f4; half8 h; } bv;
                bv.f4 = bqv[s];
                acc[tt] = __builtin_amdgcn_mfma_f32_16x16x32_f16(av.h, bv.h, acc[tt], 0, 0, 0);
            }
        }

        // ---- epilogue: D row = g*4+j (per 16-row tile), col = e ; t = t0 + w + 4*row ----
        #pragma unroll
        for (int tt = 0; tt < 4; tt++) {
            #pragma unroll
            for (int j = 0; j < 4; j++) {
                int row = tt * 16 + g * 4 + j;
                int t = t0 + w + 4 * row;
                float v = acc[tt][j] * (1.0f / 480.0f);
                if (t == SS - 1) v = 0.f;        // reference zero-pads the last position
                out[((size_t)b * SS + t) * EE + e] = v;
            }
        }
    }
}

extern "C" void kernel_launch(void* const* d_in, const int* in_sizes, int n_in,
                              void* d_out, int out_size, void* d_ws, size_t ws_size,
                              hipStream_t stream) {
    const float* x = (const float*)d_in[0];
    const float* tpl = (const float*)d_in[1];
    const float* dly = (const float*)d_in[2];
    float* out = (float*)d_out;

    int grid = BB * (SS / (TBLK * NT));   // 2048 blocks, 256 threads (4 independent waves)
    if (ws_size >= (size_t)(EE * KK * sizeof(_Float16))) {
        _Float16* wrev = (_Float16*)d_ws;
        prep_kernel<<<(EE * KK + 255) / 256, 256, 0, stream>>>(tpl, dly, wrev);
        corr_kernel<true><<<grid, 256, 0, stream>>>(x, tpl, dly, wrev, out);
    } else {
        corr_kernel<false><<<grid, 256, 0, stream>>>(x, tpl, dly, nullptr, out);
    }
}

// Round 7
// 137.872 us; speedup vs baseline: 1.0802x; 1.0802x over previous
//
#include <hip/hip_runtime.h>

// Problem constants (fixed by setup_inputs): x(64,32768,6) f32, templates(16,6,80), delays(16,6)
#define BB 64
#define SS 32768
#define FF 6
#define EE 16
#define LL 80
#define KK 480      // F*L
#define NSL 15      // K / 32
#define TBLK 256    // time positions per tile
#define NT 4        // tiles per block
#define NPHI 4      // phases (t = t0 + phi + 4*row)
#define WROW 332    // slab row length in elems (exactly 332 needed)
#define NUNITS 664  // NPHI * 166 position-pairs per tile

typedef _Float16 half8 __attribute__((ext_vector_type(8)));
typedef float f32x4 __attribute__((ext_vector_type(4)));
typedef __fp16 h2 __attribute__((ext_vector_type(2)));

// Build reversed, delay-shifted kernel: wrev[e*480 + f*80 + r] = delayed[e,f,79-r]
__global__ void prep_kernel(const float* __restrict__ tpl, const float* __restrict__ dly,
                            _Float16* __restrict__ wrev) {
    int n = blockIdx.x * 256 + threadIdx.x;
    if (n >= EE * KK) return;
    int e = n / KK, k = n - e * KK;
    int f = k / LL, r = k - f * LL;
    int m = LL - 1 - r;
    float dl = fminf(fmaxf(dly[e * FF + f], -10.f), 10.f);
    int d = (int)rintf(dl);                 // RNE, matches jnp.round
    int src = m - d;
    float v = (src >= 0 && src < LL) ? tpl[(e * FF + f) * LL + src] : 0.f;
    wrev[n] = (_Float16)v;                  // NOT pre-scaled (avoid f16 denormals)
}

// Issue global loads for one tile's staging (no LDS writes; results live in va)
__device__ __forceinline__ void stage_loads(const float* __restrict__ xb, int t0, int tid,
                                            float va[3][12]) {
    #pragma unroll
    for (int c = 0; c < 3; c++) {
        int u = tid + 256 * c;
        if (c == 2 && u >= NUNITS) continue;
        int phi = u / 166;
        int i2 = (u - phi * 166) * 2;
        int pos = t0 + phi - 39 + i2;
        if (pos >= 0 && pos <= SS - 2) {
            const float* xp = xb + (size_t)pos * FF;   // 12 contiguous floats, 8B-aligned
            #pragma unroll
            for (int q = 0; q < 6; q++)
                *(float2*)&va[c][2 * q] = *(const float2*)&xp[2 * q];
        } else {
            #pragma unroll
            for (int q = 0; q < 2; q++) {
                int p = pos + q;
                bool ok = (p >= 0) && (p < SS);
                #pragma unroll
                for (int f = 0; f < FF; f++)
                    va[c][q * 6 + f] = ok ? xb[(size_t)p * FF + f] : 0.f;
            }
        }
    }
}

// Convert + write staged values into a slab buffer
__device__ __forceinline__ void stage_write(_Float16* __restrict__ dst, int tid,
                                            float va[3][12]) {
    #pragma unroll
    for (int c = 0; c < 3; c++) {
        int u = tid + 256 * c;
        if (c == 2 && u >= NUNITS) continue;
        int phi = u / 166;
        int i2 = (u - phi * 166) * 2;
        _Float16* slab = dst + phi * (FF * WROW);
        #pragma unroll
        for (int f = 0; f < FF; f++) {
            h2 hp = __builtin_amdgcn_cvt_pkrtz(va[c][f], va[c][6 + f]);
            *(h2*)&slab[f * WROW + i2] = hp;   // 4B-aligned
        }
    }
}

template <bool FROM_WS>
__global__ __launch_bounds__(256, 3) void corr_kernel(   // 3 waves/EU -> ~170-reg budget (NO spill)
    const float* __restrict__ x, const float* __restrict__ tpl,
    const float* __restrict__ dly, const _Float16* __restrict__ wrev,
    float* __restrict__ out) {
    __shared__ alignas(16) _Float16 xs[2][NPHI][FF][WROW];   // 31,872 B double buffer

    int tid = threadIdx.x;
    int lane = tid & 63;
    int w = tid >> 6;                     // wave id == phase
    int e = lane & 15;
    int g = lane >> 4;

    int b = blockIdx.x >> 5;              // 64 batches x 32 blocks
    int T0 = (blockIdx.x & 31) << 10;     // 1024 positions per block

    const float* xb = x + (size_t)b * (SS * FF);

    // ---- B fragments into registers (15 x 16B = 60 regs, parked in AGPRs), pinned ----
    f32x4 bqv[NSL];
    if constexpr (FROM_WS) {
        #pragma unroll
        for (int s = 0; s < NSL; s++)
            bqv[s] = *(const f32x4*)&wrev[e * KK + 32 * s + 8 * g];   // 16B aligned, L2/L3-hit
    } else {
        #pragma unroll
        for (int s = 0; s < NSL; s++) {
            union { f32x4 f4; _Float16 h[8]; } u;
            #pragma unroll
            for (int j = 0; j < 8; j++) {
                int k = 32 * s + 8 * g + j;
                int f = k / LL, r = k - f * LL;
                int m = LL - 1 - r;
                float dl = fminf(fmaxf(dly[e * FF + f], -10.f), 10.f);
                int d = (int)rintf(dl);
                int src = m - d;
                u.h[j] = (_Float16)((src >= 0 && src < LL) ? tpl[(e * FF + f) * LL + src] : 0.f);
            }
            bqv[s] = u.f4;
        }
    }
    #pragma unroll
    for (int s = 0; s < NSL; s++)
        asm volatile("" : "+v"(bqv[s]));   // pin: cannot be sunk/rematerialized

    // ---- prologue: stage tile 0 into buf 0 ----
    {
        float va[3][12];
        stage_loads(xb, T0, tid, va);
        stage_write(&xs[0][0][0][0], tid, va);
    }
    __syncthreads();

    for (int i = 0; i < NT; i++) {
        int t0 = T0 + (i << 8);

        // (1) issue next tile's global loads — vmcnt wait lands AFTER the MFMA phase
        float va[3][12];
        bool have_next = (i + 1 < NT);
        if (have_next)
            stage_loads(xb, t0 + TBLK, tid, va);

        // (2) compute current tile from buf[i&1] (ds_reads precede any ds_writes below)
        const char* xph = (const char*)&xs[i & 1][w][0][0];
        f32x4 acc[4];
        #pragma unroll
        for (int tt = 0; tt < 4; tt++) acc[tt] = (f32x4){0.f, 0.f, 0.f, 0.f};
        #pragma unroll
        for (int tt = 0; tt < 4; tt++) {
            int R = tt * 16 + e;          // A-row position index (t-stride 4)
            #pragma unroll
            for (int s = 0; s < NSL; s++) {
                int k0 = 32 * s + 8 * g;
                int f = (k0 * 205) >> 14;        // exact k0/80 for k0 in [0,480)
                int r0 = k0 - 80 * f;
                const char* p = xph + 2 * (f * WROW + 4 * R + r0);   // 8B-aligned
                uint2 lo = *(const uint2*)p;
                uint2 hi = *(const uint2*)(p + 8);
                union { unsigned u[4]; half8 h; } av;
                av.u[0] = lo.x; av.u[1] = lo.y; av.u[2] = hi.x; av.u[3] = hi.y;
                union { f32x4 f4; half8 h; } bv;
                bv.f4 = bqv[s];
                acc[tt] = __builtin_amdgcn_mfma_f32_16x16x32_f16(av.h, bv.h, acc[tt], 0, 0, 0);
            }
        }

        // (3) convert + write next tile into the other buffer
        if (have_next)
            stage_write(&xs[(i + 1) & 1][0][0][0], tid, va);

        // (4) epilogue: D row = g*4+j (per 16-row tile), col = e ; t = t0 + w + 4*row
        #pragma unroll
        for (int tt = 0; tt < 4; tt++) {
            #pragma unroll
            for (int j = 0; j < 4; j++) {
                int row = tt * 16 + g * 4 + j;
                int t = t0 + w + 4 * row;
                float v = acc[tt][j] * (1.0f / 480.0f);
                if (t == SS - 1) v = 0.f;        // reference zero-pads the last position
                out[((size_t)b * SS + t) * EE + e] = v;
            }
        }

        __syncthreads();
    }
}

extern "C" void kernel_launch(void* const* d_in, const int* in_sizes, int n_in,
                              void* d_out, int out_size, void* d_ws, size_t ws_size,
                              hipStream_t stream) {
    const float* x = (const float*)d_in[0];
    const float* tpl = (const float*)d_in[1];
    const float* dly = (const float*)d_in[2];
    float* out = (float*)d_out;

    int grid = BB * (SS / (TBLK * NT));   // 2048 blocks, 256 threads (4 waves)
    if (ws_size >= (size_t)(EE * KK * sizeof(_Float16))) {
        _Float16* wrev = (_Float16*)d_ws;
        prep_kernel<<<(EE * KK + 255) / 256, 256, 0, stream>>>(tpl, dly, wrev);
        corr_kernel<true><<<grid, 256, 0, stream>>>(x, tpl, dly, wrev, out);
    } else {
        corr_kernel<false><<<grid, 256, 0, stream>>>(x, tpl, dly, nullptr, out);
    }
}

// Round 8
// 73.975 us; speedup vs baseline: 2.0133x; 1.8638x over previous
//
#include <hip/hip_runtime.h>

// Problem constants (fixed by setup_inputs): x(64,32768,6) f32, templates(16,6,80), delays(16,6)
#define BB 64
#define SS 32768
#define FF 6
#define EE 16
#define LL 80
#define KK 480      // F*L
#define NSL 15      // K / 32
#define TBLK 256    // time positions per block
#define NPHI 4      // phases (t = t0 + phi + 4*row)
#define WROW 336    // slab row length in elems (332 needed, padded)
#define UPP 166     // position-pairs per phase
#define NUNITS 664  // NPHI * UPP

typedef _Float16 half8 __attribute__((ext_vector_type(8)));
typedef float f32x4 __attribute__((ext_vector_type(4)));
typedef __fp16 h2 __attribute__((ext_vector_type(2)));

// Build reversed, delay-shifted kernel: wrev[e*480 + f*80 + r] = delayed[e,f,79-r]
__global__ void prep_kernel(const float* __restrict__ tpl, const float* __restrict__ dly,
                            _Float16* __restrict__ wrev) {
    int n = blockIdx.x * 256 + threadIdx.x;
    if (n >= EE * KK) return;
    int e = n / KK, k = n - e * KK;
    int f = k / LL, r = k - f * LL;
    int m = LL - 1 - r;
    float dl = fminf(fmaxf(dly[e * FF + f], -10.f), 10.f);
    int d = (int)rintf(dl);                 // RNE, matches jnp.round
    int src = m - d;
    float v = (src >= 0 && src < LL) ? tpl[(e * FF + f) * LL + src] : 0.f;
    wrev[n] = (_Float16)v;                  // NOT pre-scaled (avoid f16 denormals)
}

template <bool FROM_WS>
__global__ __launch_bounds__(128, 4) void corr_kernel(   // 2 waves; target <=128 unified regs
    const float* __restrict__ x, const float* __restrict__ tpl,
    const float* __restrict__ dly, const _Float16* __restrict__ wrev,
    float* __restrict__ out) {
    __shared__ alignas(16) _Float16 xs[NPHI][FF][WROW];   // 16,128 B

    int tid = threadIdx.x;
    int lane = tid & 63;
    int w = tid >> 6;                     // wave id (0..1)
    int e = lane & 15;
    int g = lane >> 4;

    int b = blockIdx.x >> 7;              // 128 t-blocks per batch
    int t0 = (blockIdx.x & 127) << 8;     // *256

    const float* xb = x + (size_t)b * (SS * FF);

    // ---- B fragments into registers (15 x 16B = 60 regs, parked in AGPRs), pinned ----
    f32x4 bqv[NSL];
    if constexpr (FROM_WS) {
        #pragma unroll
        for (int s = 0; s < NSL; s++)
            bqv[s] = *(const f32x4*)&wrev[e * KK + 32 * s + 8 * g];   // 16B aligned, L2/L3-hit
    } else {
        #pragma unroll
        for (int s = 0; s < NSL; s++) {
            union { f32x4 f4; _Float16 h[8]; } u;
            #pragma unroll
            for (int j = 0; j < 8; j++) {
                int k = 32 * s + 8 * g + j;
                int f = k / LL, r = k - f * LL;
                int m = LL - 1 - r;
                float dl = fminf(fmaxf(dly[e * FF + f], -10.f), 10.f);
                int d = (int)rintf(dl);
                int src = m - d;
                u.h[j] = (_Float16)((src >= 0 && src < LL) ? tpl[(e * FF + f) * LL + src] : 0.f);
            }
            bqv[s] = u.f4;
        }
    }
    #pragma unroll
    for (int s = 0; s < NSL; s++)
        asm volatile("" : "+v"(bqv[s]));   // pin: cannot be sunk/rematerialized

    // ---- cooperative stage: 664 pair-units over 128 threads (nothing held across compute) ----
    bool edge = (t0 - 39 < 0) | (t0 + 296 > SS);   // block-uniform
    for (int u = tid; u < NUNITS; u += 128) {
        int phi = u / UPP;
        int i2 = (u - phi * UPP) * 2;
        int pos = t0 + phi - 39 + i2;
        float va[12];
        if (!edge) {
            const float* xp = xb + (size_t)pos * FF;   // 12 contiguous floats, 8B-aligned
            #pragma unroll
            for (int q = 0; q < 6; q++)
                *(float2*)&va[2 * q] = *(const float2*)&xp[2 * q];
        } else {
            #pragma unroll
            for (int q = 0; q < 2; q++) {
                int p = pos + q;
                bool ok = (p >= 0) && (p < SS);
                #pragma unroll
                for (int f = 0; f < FF; f++)
                    va[q * 6 + f] = ok ? xb[(size_t)p * FF + f] : 0.f;
            }
        }
        #pragma unroll
        for (int f = 0; f < FF; f++) {
            h2 hp = __builtin_amdgcn_cvt_pkrtz(va[f], va[6 + f]);
            *(h2*)&xs[phi][f][i2] = hp;   // 4B-aligned
        }
    }
    __syncthreads();

    // ---- compute: per (phi, tt) tile -> MFMA x15 -> immediate store (acc live-set = 4) ----
    #pragma unroll
    for (int phi = 0; phi < NPHI; phi++) {
        const char* xph = (const char*)&xs[phi][0][0];
        #pragma unroll
        for (int tt = 0; tt < 2; tt++) {
            int R = 32 * w + 16 * tt + e;     // A-row position index (t-stride 4)
            f32x4 acc = {0.f, 0.f, 0.f, 0.f};
            #pragma unroll
            for (int s = 0; s < NSL; s++) {
                int k0 = 32 * s + 8 * g;
                int f = (k0 * 205) >> 14;        // exact k0/80 for k0 in [0,480)
                int r0 = k0 - 80 * f;
                const char* p = xph + 2 * (f * WROW + 4 * R + r0);   // 8B-aligned
                uint2 lo = *(const uint2*)p;
                uint2 hi = *(const uint2*)(p + 8);
                union { unsigned u[4]; half8 h; } av;
                av.u[0] = lo.x; av.u[1] = lo.y; av.u[2] = hi.x; av.u[3] = hi.y;
                union { f32x4 f4; half8 h; } bv;
                bv.f4 = bqv[s];
                acc = __builtin_amdgcn_mfma_f32_16x16x32_f16(av.h, bv.h, acc, 0, 0, 0);
            }
            // D layout: row = g*4 + j, col = e ; t = t0 + phi + 4*(32w + 16tt + row)
            #pragma unroll
            for (int j = 0; j < 4; j++) {
                int row = 32 * w + 16 * tt + g * 4 + j;
                int t = t0 + phi + 4 * row;
                float v = acc[j] * (1.0f / 480.0f);
                if (t == SS - 1) v = 0.f;        // reference zero-pads the last position
                out[((size_t)b * SS + t) * EE + e] = v;
            }
        }
    }
}

extern "C" void kernel_launch(void* const* d_in, const int* in_sizes, int n_in,
                              void* d_out, int out_size, void* d_ws, size_t ws_size,
                              hipStream_t stream) {
    const float* x = (const float*)d_in[0];
    const float* tpl = (const float*)d_in[1];
    const float* dly = (const float*)d_in[2];
    float* out = (float*)d_out;

    int grid = BB * (SS / TBLK);   // 16384 blocks, 128 threads (2 waves)
    if (ws_size >= (size_t)(EE * KK * sizeof(_Float16))) {
        _Float16* wrev = (_Float16*)d_ws;
        prep_kernel<<<(EE * KK + 255) / 256, 256, 0, stream>>>(tpl, dly, wrev);
        corr_kernel<true><<<grid, 128, 0, stream>>>(x, tpl, dly, wrev, out);
    } else {
        corr_kernel<false><<<grid, 128, 0, stream>>>(x, tpl, dly, nullptr, out);
    }
}